// Round 5
// baseline (226.830 us; speedup 1.0000x reference)
//
#include <hip/hip_runtime.h>
#include <hip/hip_bf16.h>

// GraphConv: out = sum_a att[a] * (adj_a @ (X@W + b))
// N=8192, A=3, D_IN=256, D_OUT=64. fp32 in/out.
// Stacked-K GEMM  C[8192,64] = [adj0|adj1|adj2] @ [att0*S; att1*S; att2*S],
// S = X@W+b in bf16, packed in MFMA-B-fragment order (d_ws).
// R5: R4 structure (LDS-staged A, 1KB-contiguous global loads) plus:
//  - per-block K-phase stagger (c0 = bid % NCHUNK): spreads instantaneous
//    DRAM traffic across all channels (row stride 32KB/strip stride 512KB
//    are channel-bit-invariant -> without stagger all blocks hammer the
//    same channel subset in lockstep) and desyncs barrier convoys.
//  - BK 512->1024: halves barrier/drain overhead, 4KB contiguous per row.

#define NNODES 8192
#define DIN    256
#define DOUT   64
#define NA     3
#define KSTACK (NA * NNODES)          // 24576
#define BK     1024
#define CPA    (NNODES / BK)          // 8 chunks per adjacency
#define NCHUNK (NA * CPA)             // 24
#define STRIP  16
#define LDSROW (BK + 8)               // 1032 ushorts (+16B pad)

typedef float f32x4 __attribute__((ext_vector_type(4)));
typedef short s16x8 __attribute__((ext_vector_type(8)));
typedef short s16x4 __attribute__((ext_vector_type(4)));

__device__ __forceinline__ unsigned short f2bf(float f) {
    __hip_bfloat16 h = __float2bfloat16(f);   // hw RNE cvt, compiler packs
    return __builtin_bit_cast(unsigned short, h);
}

__device__ __forceinline__ s16x4 pack4(f32x4 v) {
    s16x4 w;
    w[0] = (short)f2bf(v[0]); w[1] = (short)f2bf(v[1]);
    w[2] = (short)f2bf(v[2]); w[3] = (short)f2bf(v[3]);
    return w;
}

// ---------------------------------------------------------------------------
// Kernel 1: S[m][d] = sum_k X[m][k]*W[k][d] + b[d]; write att[a]*S in packed
// bf16 B-fragment layout: tile (a,kt,nt) holds B[k_local][col] with
// k_local = (lane>>4)*8 + j, col = lane&15; flat = tile*512 + lane*8 + j.
// ---------------------------------------------------------------------------
__global__ __launch_bounds__(256) void prep_support(
    const float* __restrict__ x, const float* __restrict__ w,
    const float* __restrict__ bias, const float* __restrict__ att,
    unsigned short* __restrict__ Bp)
{
    const int t = threadIdx.x;
    const int d = t & 63;
    const int m = (blockIdx.x << 2) + (t >> 6);

    const float* xr = x + (size_t)m * DIN;
    float acc = bias[d];
#pragma unroll 4
    for (int k = 0; k < DIN; k += 4) {
        f32x4 xv = *(const f32x4*)(xr + k);
        acc += xv[0] * w[(k + 0) * DOUT + d];
        acc += xv[1] * w[(k + 1) * DOUT + d];
        acc += xv[2] * w[(k + 2) * DOUT + d];
        acc += xv[3] * w[(k + 3) * DOUT + d];
    }

    const int kt   = m >> 5;
    const int kl   = m & 31;
    const int lane = ((kl >> 3) << 4) | (d & 15);
    const int j    = kl & 7;
    const int nt   = d >> 4;

    const size_t base    = (size_t)(kt * 4 + nt) * 512 + lane * 8 + j;
    const size_t aStride = (size_t)(NNODES / 32) * 4 * 512;  // 524288 elems/adjacency

    const float a0 = att[0], a1 = att[1], a2 = att[2];
    Bp[base]               = f2bf(a0 * acc);
    Bp[base + aStride]     = f2bf(a1 * acc);
    Bp[base + 2 * aStride] = f2bf(a2 * acc);
}

// ---------------------------------------------------------------------------
// Kernel 2: block = 16-row strip, walks all 24 chunks of stacked K starting
// at phase c0 = bid % 24 (wraps). Per chunk: each wave stages 4 rows x 4KB
// (1KB-contiguous dwordx4 loads, issued before the MFMA phase), cvt->bf16,
// ds_write; MFMA reads fragments from the other LDS buffer. 4 waves split
// the chunk's 32 k-tiles. LDS cross-wave reduce, direct stores.
// ---------------------------------------------------------------------------
__global__ __launch_bounds__(256, 2) void graphconv_gemm(
    const float* __restrict__ adj, const unsigned short* __restrict__ Bp,
    float* __restrict__ out)
{
    __shared__ unsigned short lds[2][STRIP][LDSROW];   // 2 x 33 KB

    const int tid  = threadIdx.x;
    const int wave = tid >> 6;
    const int lane = tid & 63;
    const int r    = lane & 15;   // A row within tile / C col
    const int g    = lane >> 4;   // k-subgroup
    const int strip = blockIdx.x;
    const int row0  = strip * STRIP;
    const int c0    = blockIdx.x % NCHUNK;

    const s16x8* __restrict__ Bv = (const s16x8*)Bp;

    f32x4 acc0 = {0.f, 0.f, 0.f, 0.f};
    f32x4 acc1 = {0.f, 0.f, 0.f, 0.f};
    f32x4 acc2 = {0.f, 0.f, 0.f, 0.f};
    f32x4 acc3 = {0.f, 0.f, 0.f, 0.f};

    // ---- prologue: stage chunk c0 into buffer 0
    {
        const float* ab = adj + ((size_t)(c0 >> 3) << 26) + ((size_t)(c0 & 7) << 10);
#pragma unroll
        for (int p = 0; p < 4; ++p) {
            const int lr = (wave << 2) + p;
            const float* rp = ab + (size_t)(row0 + lr) * NNODES + lane * 4;
#pragma unroll
            for (int q = 0; q < 4; ++q) {
                f32x4 v = __builtin_nontemporal_load((const f32x4*)(rp + q * 256));
                *(s16x4*)&lds[0][lr][(q << 8) + (lane << 2)] = pack4(v);
            }
        }
    }

    int c = c0;
    for (int i = 0; i < NCHUNK; ++i) {
        const int cur = i & 1;
        __syncthreads();

        // issue global loads for the next chunk (hide HBM under MFMA phase)
        const int cn = (c == NCHUNK - 1) ? 0 : c + 1;
        f32x4 nv[4][4];
        const bool more = (i + 1 < NCHUNK);
        if (more) {
            const float* ab = adj + ((size_t)(cn >> 3) << 26) + ((size_t)(cn & 7) << 10);
#pragma unroll
            for (int p = 0; p < 4; ++p) {
                const int lr = (wave << 2) + p;
                const float* rp = ab + (size_t)(row0 + lr) * NNODES + lane * 4;
#pragma unroll
                for (int q = 0; q < 4; ++q)
                    nv[p][q] = __builtin_nontemporal_load((const f32x4*)(rp + q * 256));
            }
        }

        // compute: wave's 8 k-tiles of chunk c
        const s16x8* bp = Bv + ((size_t)(c << 5) + (wave << 3)) * 256 + lane;
#pragma unroll 4
        for (int t = 0; t < 8; ++t) {
            const s16x8 af = *(const s16x8*)&lds[cur][r][(wave << 8) + (t << 5) + (g << 3)];
            s16x8 b0 = bp[0];
            s16x8 b1 = bp[64];
            s16x8 b2 = bp[128];
            s16x8 b3 = bp[192];
            acc0 = __builtin_amdgcn_mfma_f32_16x16x32_bf16(af, b0, acc0, 0, 0, 0);
            acc1 = __builtin_amdgcn_mfma_f32_16x16x32_bf16(af, b1, acc1, 0, 0, 0);
            acc2 = __builtin_amdgcn_mfma_f32_16x16x32_bf16(af, b2, acc2, 0, 0, 0);
            acc3 = __builtin_amdgcn_mfma_f32_16x16x32_bf16(af, b3, acc3, 0, 0, 0);
            bp += 256;
        }

        // write staged chunk into the other buffer
        if (more) {
#pragma unroll
            for (int p = 0; p < 4; ++p) {
                const int lr = (wave << 2) + p;
#pragma unroll
                for (int q = 0; q < 4; ++q)
                    *(s16x4*)&lds[cur ^ 1][lr][(q << 8) + (lane << 2)] = pack4(nv[p][q]);
            }
        }

        c = cn;
    }

    // ---- cross-wave reduce: overlay fp32 red[4][16][64] on buffer 0
    __syncthreads();
    float* red = (float*)&lds[0][0][0];
    // C/D layout (m89-verified): per 16x16 tile, col = r, row = g*4 + j
#pragma unroll
    for (int j = 0; j < 4; ++j) {
        const int row = (g << 2) + j;
        float* rp = red + ((wave * 16 + row) << 6) + r;
        rp[0]  = acc0[j];
        rp[16] = acc1[j];
        rp[32] = acc2[j];
        rp[48] = acc3[j];
    }
    __syncthreads();

    const f32x4* redv = (const f32x4*)red;
    f32x4 s = redv[tid] + redv[256 + tid] + redv[512 + tid] + redv[768 + tid];
    ((f32x4*)out)[(strip << 8) + tid] = s;
}

// ---------------------------------------------------------------------------
extern "C" void kernel_launch(void* const* d_in, const int* in_sizes, int n_in,
                              void* d_out, int out_size, void* d_ws, size_t ws_size,
                              hipStream_t stream) {
    const float* x   = (const float*)d_in[0];   // [8192, 256]
    const float* adj = (const float*)d_in[1];   // [3, 8192, 8192]
    const float* att = (const float*)d_in[2];   // [3]
    const float* w   = (const float*)d_in[3];   // [256, 64]
    const float* b   = (const float*)d_in[4];   // [64]
    float* out = (float*)d_out;                 // [8192, 64] fp32
    unsigned short* Bp = (unsigned short*)d_ws; // 3 MB packed bf16 B operand

    prep_support<<<NNODES / 4, 256, 0, stream>>>(x, w, b, att, Bp);
    graphconv_gemm<<<NNODES / STRIP, 256, 0, stream>>>(adj, Bp, out);
}

// Round 6
// 185.174 us; speedup vs baseline: 1.2250x; 1.2250x over previous
//
#include <hip/hip_runtime.h>
#include <hip/hip_bf16.h>

// GraphConv: out = sum_a att[a] * (adj_a @ (X@W + b))
// N=8192, A=3, D_IN=256, D_OUT=64. fp32 in/out.
// Stacked-K GEMM  C[8192,64] = [adj0|adj1|adj2] @ [att0*S; att1*S; att2*S],
// S = X@W+b in bf16, packed MFMA-B-fragment order (d_ws).
// R6: barrier-free wave-private design. Block = 64-row strip x K-quarter;
// each wave = 16 rows x 6144 k, own 16KB LDS buffer, zero cross-wave deps.
// A staged via global_load_lds (width16, NT): 1 instruction = 1 row x 1KB
// contiguous. Source-side XOR swizzle -> bank-uniform ds_read_b128.
// 8 free-running waves/CU keep ~100KB outstanding to HBM continuously.
// K-split partials in ws + reduce kernel (atomic fallback if ws small).

#define NNODES 8192
#define DIN    256
#define DOUT   64
#define NA     3
#define KSTACK (NA * NNODES)     // 24576
#define KQ     (KSTACK / 4)      // 6144 per block
#define BK     256
#define NCH    (KQ / BK)         // 24 chunks per wave
#define NSTRIP (NNODES / 64)     // 128

typedef float f32x4 __attribute__((ext_vector_type(4)));
typedef short s16x8 __attribute__((ext_vector_type(8)));

__device__ __forceinline__ unsigned short f2bf(float f) {
    __hip_bfloat16 h = __float2bfloat16(f);
    return __builtin_bit_cast(unsigned short, h);
}

__device__ __forceinline__ s16x8 pack8(f32x4 a, f32x4 b) {
    s16x8 o;
    o[0] = (short)f2bf(a[0]); o[1] = (short)f2bf(a[1]);
    o[2] = (short)f2bf(a[2]); o[3] = (short)f2bf(a[3]);
    o[4] = (short)f2bf(b[0]); o[5] = (short)f2bf(b[1]);
    o[6] = (short)f2bf(b[2]); o[7] = (short)f2bf(b[3]);
    return o;
}

__device__ __forceinline__ void gload_lds16(const float* g, float* l) {
    // width 16B, offset 0, aux=2 (NT: adj is single-use, keep B in L2)
    __builtin_amdgcn_global_load_lds(
        (const __attribute__((address_space(1))) void*)g,
        (__attribute__((address_space(3))) void*)l, 16, 0, 2);
}

// ---------------------------------------------------------------------------
// Kernel 0: zero d_out (atomic fallback only).
// ---------------------------------------------------------------------------
__global__ __launch_bounds__(256) void zero_out(float* __restrict__ out) {
    f32x4 z = {0.f, 0.f, 0.f, 0.f};
    ((f32x4*)out)[(blockIdx.x << 8) + threadIdx.x] = z;
}

// ---------------------------------------------------------------------------
// Kernel 1: S = X@W + b; write att[a]*S in packed bf16 B-fragment layout:
// tile (kt_abs, nt): B[k_local][col], k_local = (lane>>4)*8 + j, col = lane&15;
// flat shorts = (kt_abs*4 + nt)*512 + lane*8 + j.
// ---------------------------------------------------------------------------
__global__ __launch_bounds__(256) void prep_support(
    const float* __restrict__ x, const float* __restrict__ w,
    const float* __restrict__ bias, const float* __restrict__ att,
    unsigned short* __restrict__ Bp)
{
    const int t = threadIdx.x;
    const int d = t & 63;
    const int m = (blockIdx.x << 2) + (t >> 6);

    const float* xr = x + (size_t)m * DIN;
    float acc = bias[d];
#pragma unroll 4
    for (int k = 0; k < DIN; k += 4) {
        f32x4 xv = *(const f32x4*)(xr + k);
        acc += xv[0] * w[(k + 0) * DOUT + d];
        acc += xv[1] * w[(k + 1) * DOUT + d];
        acc += xv[2] * w[(k + 2) * DOUT + d];
        acc += xv[3] * w[(k + 3) * DOUT + d];
    }

    const int kt   = m >> 5;
    const int kl   = m & 31;
    const int lane = ((kl >> 3) << 4) | (d & 15);
    const int j    = kl & 7;
    const int nt   = d >> 4;

    const size_t base    = (size_t)(kt * 4 + nt) * 512 + lane * 8 + j;
    const size_t aStride = (size_t)(NNODES / 32) * 4 * 512;

    const float a0 = att[0], a1 = att[1], a2 = att[2];
    Bp[base]               = f2bf(a0 * acc);
    Bp[base + aStride]     = f2bf(a1 * acc);
    Bp[base + 2 * aStride] = f2bf(a2 * acc);
}

// ---------------------------------------------------------------------------
// Kernel 2: bid = strip*4 + q. Wave wv owns rows [strip*64 + wv*16, +16) and
// k in [q*6144, +6144), walked as 24 chunks of 256 (staggered start).
// Per chunk: 16x global_load_lds (row-contiguous 1KB each, XOR-preswizzled
// source), vmcnt(0), then 8 k-tiles of {2 ds_read_b128, pack, 4 B-frag
// loads (L2, XCD-pinned slice), 4 mfma_16x16x32_bf16}. No barriers.
// ---------------------------------------------------------------------------
template <bool ATOMIC>
__global__ __launch_bounds__(256, 2) void graphconv_gemm(
    const float* __restrict__ adj, const unsigned short* __restrict__ Bp,
    float* __restrict__ dst)   // partials base (false) or out (true)
{
    __shared__ float ldsf[16384];            // 64 KB: wave wv -> [wv*4096, +4096)

    const int tid  = threadIdx.x;
    const int wv   = tid >> 6;
    const int lane = tid & 63;
    const int r    = lane & 15;              // A row within tile / C col
    const int g    = lane >> 4;              // k-subgroup
    const int r7   = r & 7;
    const int q     = blockIdx.x & 3;        // K-quarter (XCD-pinned B slice)
    const int strip = blockIdx.x >> 2;
    const int row0  = strip * 64 + wv * 16;

    float* wbuf = &ldsf[wv << 12];           // 16 KB wave-private buffer

    f32x4 acc0 = {0.f, 0.f, 0.f, 0.f};
    f32x4 acc1 = {0.f, 0.f, 0.f, 0.f};
    f32x4 acc2 = {0.f, 0.f, 0.f, 0.f};
    f32x4 acc3 = {0.f, 0.f, 0.f, 0.f};

    const int c0 = (wv * 6 + strip) % NCH;   // desync k-walk phases

    for (int i = 0; i < NCH; ++i) {
        int c = c0 + i; if (c >= NCH) c -= NCH;
        const int k0 = q * KQ + c * BK;                        // stacked k
        const float* ab = adj + ((size_t)(k0 >> 13) << 26) + (k0 & 8191);

        // stage 16 rows x 1KB, linear LDS dest + XOR-preswizzled source
#pragma unroll
        for (int p = 0; p < 16; ++p) {
            const float* gp = ab + (size_t)(row0 + p) * NNODES
                                 + ((lane ^ (p & 7)) << 2);
            gload_lds16(gp, wbuf + (p << 8));
        }
        asm volatile("s_waitcnt vmcnt(0)" ::: "memory");
        __builtin_amdgcn_sched_barrier(0);

        const s16x8* bp = (const s16x8*)Bp + ((size_t)(k0 >> 5) << 8) + lane;
        const float* lrow = wbuf + (r << 8);
#pragma unroll
        for (int t = 0; t < 8; ++t) {
            // fragment floats [t*32+g*8, +8): slots (2g)^r7, (2g+1)^r7
            f32x4 v0 = *(const f32x4*)(lrow + ((t * 8 + ((2 * g) ^ r7)) << 2));
            f32x4 v1 = *(const f32x4*)(lrow + ((t * 8 + ((2 * g + 1) ^ r7)) << 2));
            s16x8 af = pack8(v0, v1);
            s16x8 b0 = bp[0];
            s16x8 b1 = bp[64];
            s16x8 b2 = bp[128];
            s16x8 b3 = bp[192];
            acc0 = __builtin_amdgcn_mfma_f32_16x16x32_bf16(af, b0, acc0, 0, 0, 0);
            acc1 = __builtin_amdgcn_mfma_f32_16x16x32_bf16(af, b1, acc1, 0, 0, 0);
            acc2 = __builtin_amdgcn_mfma_f32_16x16x32_bf16(af, b2, acc2, 0, 0, 0);
            acc3 = __builtin_amdgcn_mfma_f32_16x16x32_bf16(af, b3, acc3, 0, 0, 0);
            bp += 256;
        }
    }

    // D[m=4g+j][n]: lane (r,g) reg j -> row row0+4g+j, col nt*16+r
    if (ATOMIC) {
        float* op = dst + (size_t)row0 * DOUT;
#pragma unroll
        for (int j = 0; j < 4; ++j) {
            float* rp = op + (size_t)(4 * g + j) * DOUT + r;
            atomicAdd(rp,      acc0[j]);
            atomicAdd(rp + 16, acc1[j]);
            atomicAdd(rp + 32, acc2[j]);
            atomicAdd(rp + 48, acc3[j]);
        }
    } else {
        float* pp = dst + (size_t)q * (NNODES * DOUT) + (size_t)row0 * DOUT;
#pragma unroll
        for (int j = 0; j < 4; ++j) {
            float* rp = pp + (size_t)(4 * g + j) * DOUT + r;
            rp[0]  = acc0[j];
            rp[16] = acc1[j];
            rp[32] = acc2[j];
            rp[48] = acc3[j];
        }
    }
}

// ---------------------------------------------------------------------------
// Kernel 3: out = sum over 4 K-quarter partials.
// ---------------------------------------------------------------------------
__global__ __launch_bounds__(256) void reduce_partials(
    const float* __restrict__ part, float* __restrict__ out)
{
    const int i = (blockIdx.x << 8) + threadIdx.x;    // f32x4 idx, 131072 total
    const f32x4* p = (const f32x4*)part;
    f32x4 s = p[i] + p[i + 131072] + p[i + 262144] + p[i + 393216];
    ((f32x4*)out)[i] = s;
}

// ---------------------------------------------------------------------------
extern "C" void kernel_launch(void* const* d_in, const int* in_sizes, int n_in,
                              void* d_out, int out_size, void* d_ws, size_t ws_size,
                              hipStream_t stream) {
    const float* x   = (const float*)d_in[0];   // [8192, 256]
    const float* adj = (const float*)d_in[1];   // [3, 8192, 8192]
    const float* att = (const float*)d_in[2];   // [3]
    const float* w   = (const float*)d_in[3];   // [256, 64]
    const float* b   = (const float*)d_in[4];   // [64]
    float* out = (float*)d_out;                 // [8192, 64] fp32

    unsigned short* Bp = (unsigned short*)d_ws; // 3 MB packed bf16 B operand
    const size_t bpBytes   = (size_t)KSTACK * DOUT * 2;           // 3 MB
    const size_t partOff   = (bpBytes + 255) & ~(size_t)255;
    const size_t partBytes = (size_t)4 * NNODES * DOUT * 4;       // 8 MB
    const bool usePartials = ws_size >= partOff + partBytes;

    prep_support<<<NNODES / 4, 256, 0, stream>>>(x, w, b, att, Bp);

    if (usePartials) {
        float* part = (float*)((char*)d_ws + partOff);
        graphconv_gemm<false><<<NSTRIP * 4, 256, 0, stream>>>(adj, Bp, part);
        reduce_partials<<<NNODES * DOUT / 1024, 256, 0, stream>>>(part, out);
    } else {
        zero_out<<<NNODES * DOUT / 1024, 256, 0, stream>>>(out);
        graphconv_gemm<true><<<NSTRIP * 4, 256, 0, stream>>>(adj, Bp, out);
    }
}